// Round 4
// baseline (507.284 us; speedup 1.0000x reference)
//
#include <hip/hip_runtime.h>

#define H 1024
#define S 2048
#define B 32
#define M (S*B)

typedef short bf16x8 __attribute__((ext_vector_type(8)));
typedef float f32x4 __attribute__((ext_vector_type(4)));

__device__ __forceinline__ unsigned short f2bf(float f) {
    unsigned int u = __builtin_bit_cast(unsigned int, f);
    u += 0x7FFFu + ((u >> 16) & 1u);
    return (unsigned short)(u >> 16);
}

__device__ __forceinline__ void gload_lds16(const void* g, void* l) {
    __builtin_amdgcn_global_load_lds((const __attribute__((address_space(1))) void*)g,
                                     (__attribute__((address_space(3))) void*)l, 16, 0, 0);
}

// ---------------- enc f32 -> bf16 ----------------
__global__ __launch_bounds__(256) void convert_enc(const float* __restrict__ enc,
                                                   unsigned short* __restrict__ encBF) {
    const size_t total = (size_t)M * H / 8;
    for (size_t idx = (size_t)blockIdx.x * 256 + threadIdx.x; idx < total;
         idx += (size_t)gridDim.x * 256) {
        const float4* p = (const float4*)(enc + idx * 8);
        float4 x = p[0], y = p[1];
        bf16x8 c;
        c[0] = (short)f2bf(x.x); c[1] = (short)f2bf(x.y);
        c[2] = (short)f2bf(x.z); c[3] = (short)f2bf(x.w);
        c[4] = (short)f2bf(y.x); c[5] = (short)f2bf(y.y);
        c[6] = (short)f2bf(y.z); c[7] = (short)f2bf(y.w);
        *(bf16x8*)(encBF + idx * 8) = c;
    }
}

// ---------------- We -> We^T (bf16) ----------------
__global__ __launch_bounds__(256) void transpose_we(const float* __restrict__ We,
                                                    unsigned short* __restrict__ WeT) {
    __shared__ float t[64][65];
    int tx = threadIdx.x & 63, ty = threadIdx.x >> 6;
    int n0 = blockIdx.x * 64, k0 = blockIdx.y * 64;
#pragma unroll
    for (int q = 0; q < 16; ++q) {
        int kk = ty * 16 + q;
        t[kk][tx] = We[(size_t)(k0 + kk) * H + n0 + tx];
    }
    __syncthreads();
#pragma unroll
    for (int q = 0; q < 16; ++q) {
        int nn = ty * 16 + q;
        WeT[(size_t)(n0 + nn) * H + k0 + tx] = f2bf(t[tx][nn]);
    }
}

// ---------------- d[b][j] = dec[b] @ Wd ----------------
__global__ __launch_bounds__(256) void dec_proj(const float* __restrict__ dec,
                                                const float* __restrict__ Wd,
                                                float* __restrict__ dvec) {
    __shared__ float ds[H];
    int b = blockIdx.y, jc = blockIdx.x, t = threadIdx.x;
    for (int i = t; i < H; i += 256) ds[i] = dec[b * H + i];
    __syncthreads();
    int j = jc * 256 + t;
    float acc = 0.f;
#pragma unroll 8
    for (int h = 0; h < H; ++h) acc += ds[h] * Wd[(size_t)h * H + j];
    dvec[b * H + j] = acc;
}

// ---------------- 256x256 8-phase fused GEMM ----------------
// LDS: per operand [2 buf][2 half][128 rows][64 cols] bf16, row-XOR swizzled
// (physical slot = logical slot ^ (row&7); achieved by pre-swizzled global src,
// linear LDS dest for global_load_lds, XOR applied again on ds_read).
template<int CBUF, int MG, int NG, bool STG, bool DRAIN>
__device__ __forceinline__ void phase_op(unsigned short* As, unsigned short* Bs,
                                         const unsigned short* aBase,
                                         const unsigned short* bBase,
                                         int tid, int lane, int wm, int wn,
                                         int stile, f32x4 (&acc)[8][4]) {
    int l15 = lane & 15, l4 = lane >> 4;
    bf16x8 a[4][2], bq[2][2];
#pragma unroll
    for (int mi = 0; mi < 4; ++mi) {
        int rh = (MG * 4 + mi) * 16 + l15;
        int rowoff = CBUF * 16384 + wm * 8192 + rh * 64;
#pragma unroll
        for (int kk = 0; kk < 2; ++kk)
            a[mi][kk] = *(const bf16x8*)&As[rowoff + (((kk * 4 + l4) ^ (rh & 7)) * 8)];
    }
#pragma unroll
    for (int ni = 0; ni < 2; ++ni) {
        int rh = (wn & 1) * 64 + (NG * 2 + ni) * 16 + l15;
        int rowoff = CBUF * 16384 + (wn >> 1) * 8192 + rh * 64;
#pragma unroll
        for (int kk = 0; kk < 2; ++kk)
            bq[ni][kk] = *(const bf16x8*)&Bs[rowoff + (((kk * 4 + l4) ^ (rh & 7)) * 8)];
    }
    if (STG) {
#pragma unroll
        for (int q = 0; q < 4; ++q)
            gload_lds16(aBase + (size_t)q * 65536 + stile * 64,
                        &As[(CBUF ^ 1) * 16384 + q * 4096 + tid * 8]);
#pragma unroll
        for (int q = 0; q < 4; ++q)
            gload_lds16(bBase + (size_t)q * 65536 + stile * 64,
                        &Bs[(CBUF ^ 1) * 16384 + q * 4096 + tid * 8]);
    }
    __builtin_amdgcn_s_barrier();
    __builtin_amdgcn_s_setprio(1);
#pragma unroll
    for (int mi = 0; mi < 4; ++mi)
#pragma unroll
        for (int ni = 0; ni < 2; ++ni)
#pragma unroll
            for (int kk = 0; kk < 2; ++kk)
                acc[MG * 4 + mi][NG * 2 + ni] = __builtin_amdgcn_mfma_f32_16x16x32_bf16(
                    a[mi][kk], bq[ni][kk], acc[MG * 4 + mi][NG * 2 + ni], 0, 0, 0);
    __builtin_amdgcn_s_setprio(0);
    if (DRAIN) asm volatile("s_waitcnt vmcnt(0)" ::: "memory");
    __builtin_amdgcn_s_barrier();
}

__global__ __launch_bounds__(512, 2) void gemm_logits3(const unsigned short* __restrict__ encBF,
                                                       const unsigned short* __restrict__ WeT,
                                                       const float* __restrict__ dvec,
                                                       const float* __restrict__ v,
                                                       float* __restrict__ part) {
    __shared__ unsigned short As[32768];   // 64 KB
    __shared__ unsigned short Bs[32768];   // 64 KB
    int tid = threadIdx.x, bid = blockIdx.x;
    // XCD-chunked bijective swizzle (1024 blocks % 8 == 0)
    int swz = (bid & 7) * 128 + (bid >> 3);
    int bm = swz >> 2, bn = swz & 3;
    int lane = tid & 63, wid = tid >> 6;
    int wm = wid >> 2, wn = wid & 3;

    f32x4 acc[8][4] = {};

    // staging geometry: thread tid covers segments tid and tid+512 of each half
    int row0 = tid >> 3;                       // 0..63
    int slot0 = (tid & 7) ^ (row0 & 7);        // pre-swizzled source slot
    const unsigned short* aBase = encBF + (size_t)(bm * 256 + row0) * H + slot0 * 8;
    const unsigned short* bBase = WeT + (size_t)(bn * 256 + row0) * H + slot0 * 8;

    // prologue: stage tile 0 into buf0, drain
#pragma unroll
    for (int q = 0; q < 4; ++q) gload_lds16(aBase + (size_t)q * 65536, &As[q * 4096 + tid * 8]);
#pragma unroll
    for (int q = 0; q < 4; ++q) gload_lds16(bBase + (size_t)q * 65536, &Bs[q * 4096 + tid * 8]);
    asm volatile("s_waitcnt vmcnt(0)" ::: "memory");
    __builtin_amdgcn_s_barrier();

    for (int it = 0; it < 8; ++it) {
        int t1 = 2 * it + 1, t2 = 2 * it + 2;
        // phases 1-4: compute tile 2it from buf0; stage tile 2it+1 -> buf1 at phase 1
        phase_op<0, 0, 0, true, false>(As, Bs, aBase, bBase, tid, lane, wm, wn, t1, acc);
        phase_op<0, 0, 1, false, false>(As, Bs, aBase, bBase, tid, lane, wm, wn, 0, acc);
        phase_op<0, 1, 0, false, false>(As, Bs, aBase, bBase, tid, lane, wm, wn, 0, acc);
        phase_op<0, 1, 1, false, true>(As, Bs, aBase, bBase, tid, lane, wm, wn, 0, acc);
        // phases 5-8: compute tile 2it+1 from buf1; stage tile 2it+2 -> buf0 at phase 5
        if (it < 7)
            phase_op<1, 0, 0, true, false>(As, Bs, aBase, bBase, tid, lane, wm, wn, t2, acc);
        else
            phase_op<1, 0, 0, false, false>(As, Bs, aBase, bBase, tid, lane, wm, wn, 0, acc);
        phase_op<1, 0, 1, false, false>(As, Bs, aBase, bBase, tid, lane, wm, wn, 0, acc);
        phase_op<1, 1, 0, false, false>(As, Bs, aBase, bBase, tid, lane, wm, wn, 0, acc);
        phase_op<1, 1, 1, false, true>(As, Bs, aBase, bBase, tid, lane, wm, wn, 0, acc);
    }

    // epilogue: partial logit over this block's 256 j's, per wave its own 64
    float vj[4];
#pragma unroll
    for (int n = 0; n < 4; ++n) vj[n] = v[bn * 256 + wn * 64 + n * 16 + (lane & 15)];
#pragma unroll
    for (int m = 0; m < 8; ++m) {
#pragma unroll
        for (int i = 0; i < 4; ++i) {
            int rg = bm * 256 + wm * 128 + m * 16 + (lane >> 4) * 4 + i;
            int bb = rg & (B - 1);   // row = s*B + b
            float p = 0.f;
#pragma unroll
            for (int n = 0; n < 4; ++n) {
                int j = bn * 256 + wn * 64 + n * 16 + (lane & 15);
                p += vj[n] * tanhf(dvec[bb * H + j] + acc[m][n][i]);
            }
            p += __shfl_xor(p, 1);
            p += __shfl_xor(p, 2);
            p += __shfl_xor(p, 4);
            p += __shfl_xor(p, 8);
            if ((lane & 15) == 0) part[(size_t)rg * 16 + bn * 4 + wn] = p;
        }
    }
}

// ---------------- softmax over s per b ----------------
__global__ __launch_bounds__(256) void softmax_k(const float* __restrict__ part,
                                                 float* __restrict__ scores) {
    int b = blockIdx.x, tid = threadIdx.x;
    int lane = tid & 63, wid = tid >> 6;
    __shared__ float red[4];
    __shared__ float red2[4];
    float lg[8];
    float mx = -1e30f;
#pragma unroll
    for (int q = 0; q < 8; ++q) {
        int s = q * 256 + tid;
        const float4* pr = (const float4*)(part + ((size_t)(s * B + b)) * 16);
        float4 x = pr[0], y = pr[1], z = pr[2], w = pr[3];
        float L = (((x.x + x.y) + (x.z + x.w)) + ((y.x + y.y) + (y.z + y.w))) +
                  (((z.x + z.y) + (z.z + z.w)) + ((w.x + w.y) + (w.z + w.w)));
        lg[q] = L;
        mx = fmaxf(mx, L);
    }
#pragma unroll
    for (int off = 32; off; off >>= 1) mx = fmaxf(mx, __shfl_xor(mx, off));
    if (lane == 0) red[wid] = mx;
    __syncthreads();
    mx = fmaxf(fmaxf(red[0], red[1]), fmaxf(red[2], red[3]));
    float sum = 0.f;
#pragma unroll
    for (int q = 0; q < 8; ++q) {
        lg[q] = expf(lg[q] - mx);
        sum += lg[q];
    }
#pragma unroll
    for (int off = 32; off; off >>= 1) sum += __shfl_xor(sum, off);
    if (lane == 0) red2[wid] = sum;
    __syncthreads();
    sum = (red2[0] + red2[1]) + (red2[2] + red2[3]);
    float inv = 1.f / sum;
#pragma unroll
    for (int q = 0; q < 8; ++q) scores[b * S + q * 256 + tid] = lg[q] * inv;
}

// ---------------- attn_values partials: sum over an S-chunk ----------------
__global__ __launch_bounds__(256) void weighted_sum(const float* __restrict__ enc,
                                                    const float* __restrict__ scores,
                                                    float* __restrict__ part2) {
    __shared__ float sl[512];
    int t = threadIdx.x;
    int hx = blockIdx.x, b = blockIdx.y, sc = blockIdx.z;
    sl[t] = scores[b * S + sc * 512 + t];
    sl[t + 256] = scores[b * S + sc * 512 + t + 256];
    __syncthreads();
    int h = hx * 256 + t;
    const float* ep = enc + ((size_t)(sc * 512) * B) * H + (size_t)b * H + h;
    float acc = 0.f;
#pragma unroll 4
    for (int s = 0; s < 512; ++s) acc += ep[(size_t)s * B * H] * sl[s];
    part2[((size_t)sc * B + b) * H + h] = acc;
}

__global__ __launch_bounds__(256) void reduce_vals(const float* __restrict__ part2,
                                                   float* __restrict__ out) {
    int i = blockIdx.x * 256 + threadIdx.x;
    out[i] = (part2[i] + part2[B * H + i]) + (part2[2 * B * H + i] + part2[3 * B * H + i]);
}

extern "C" void kernel_launch(void* const* d_in, const int* in_sizes, int n_in,
                              void* d_out, int out_size, void* d_ws, size_t ws_size,
                              hipStream_t stream) {
    const float* dec = (const float*)d_in[0];   // [1,B,H]
    const float* enc = (const float*)d_in[1];   // [S,B,H]
    const float* Wd  = (const float*)d_in[2];   // [H,H]
    const float* We  = (const float*)d_in[3];   // [H,H]
    const float* v   = (const float*)d_in[4];   // [H]
    float* out = (float*)d_out;                 // [B*H] values, then [B*S] scores

    char* ws = (char*)d_ws;
    unsigned short* WeT = (unsigned short*)ws;                 // 2 MB
    float* dvec  = (float*)(ws + (2u << 20));                  // 128 KB
    float* part  = (float*)(ws + (3u << 20));                  // 4 MB
    float* part2 = (float*)(ws + (7u << 20));                  // 512 KB
    unsigned short* encBF = (unsigned short*)(ws + ((size_t)8 << 20));  // 128 MB

    transpose_we<<<dim3(16, 16), 256, 0, stream>>>(We, WeT);
    dec_proj<<<dim3(4, B), 256, 0, stream>>>(dec, Wd, dvec);
    convert_enc<<<2048, 256, 0, stream>>>(enc, encBF);
    gemm_logits3<<<1024, 512, 0, stream>>>(encBF, WeT, dvec, v, part);
    softmax_k<<<B, 256, 0, stream>>>(part, out + B * H);
    weighted_sum<<<dim3(4, B, 4), 256, 0, stream>>>(enc, out + B * H, part2);
    reduce_vals<<<128, 256, 0, stream>>>(part2, out);
}

// Round 5
// 473.813 us; speedup vs baseline: 1.0706x; 1.0706x over previous
//
#include <hip/hip_runtime.h>

#define H 1024
#define S 2048
#define B 32
#define M (S*B)

typedef short bf16x8 __attribute__((ext_vector_type(8)));
typedef float f32x4 __attribute__((ext_vector_type(4)));

__device__ __forceinline__ unsigned short f2bf(float f) {
    unsigned int u = __builtin_bit_cast(unsigned int, f);
    u += 0x7FFFu + ((u >> 16) & 1u);
    return (unsigned short)(u >> 16);
}

__device__ __forceinline__ void gload_lds16(const void* g, void* l) {
    __builtin_amdgcn_global_load_lds((const __attribute__((address_space(1))) void*)g,
                                     (__attribute__((address_space(3))) void*)l, 16, 0, 0);
}

// ---------------- enc f32 -> bf16 ----------------
__global__ __launch_bounds__(256) void convert_enc(const float* __restrict__ enc,
                                                   unsigned short* __restrict__ encBF) {
    const size_t total = (size_t)M * H / 8;
    for (size_t idx = (size_t)blockIdx.x * 256 + threadIdx.x; idx < total;
         idx += (size_t)gridDim.x * 256) {
        const float4* p = (const float4*)(enc + idx * 8);
        float4 x = p[0], y = p[1];
        bf16x8 c;
        c[0] = (short)f2bf(x.x); c[1] = (short)f2bf(x.y);
        c[2] = (short)f2bf(x.z); c[3] = (short)f2bf(x.w);
        c[4] = (short)f2bf(y.x); c[5] = (short)f2bf(y.y);
        c[6] = (short)f2bf(y.z); c[7] = (short)f2bf(y.w);
        *(bf16x8*)(encBF + idx * 8) = c;
    }
}

// ---------------- We -> We^T (bf16) ----------------
__global__ __launch_bounds__(256) void transpose_we(const float* __restrict__ We,
                                                    unsigned short* __restrict__ WeT) {
    __shared__ float t[64][65];
    int tx = threadIdx.x & 63, ty = threadIdx.x >> 6;
    int n0 = blockIdx.x * 64, k0 = blockIdx.y * 64;
#pragma unroll
    for (int q = 0; q < 16; ++q) {
        int kk = ty * 16 + q;
        t[kk][tx] = We[(size_t)(k0 + kk) * H + n0 + tx];
    }
    __syncthreads();
#pragma unroll
    for (int q = 0; q < 16; ++q) {
        int nn = ty * 16 + q;
        WeT[(size_t)(n0 + nn) * H + k0 + tx] = f2bf(t[tx][nn]);
    }
}

// ---------------- d[b][j] = dec[b] @ Wd ----------------
__global__ __launch_bounds__(256) void dec_proj(const float* __restrict__ dec,
                                                const float* __restrict__ Wd,
                                                float* __restrict__ dvec) {
    __shared__ float ds[H];
    int b = blockIdx.y, jc = blockIdx.x, t = threadIdx.x;
    for (int i = t; i < H; i += 256) ds[i] = dec[b * H + i];
    __syncthreads();
    int j = jc * 256 + t;
    float acc = 0.f;
#pragma unroll 8
    for (int h = 0; h < H; ++h) acc += ds[h] * Wd[(size_t)h * H + j];
    dvec[b * H + j] = acc;
}

// ---------------- 256x256 counted-vmcnt 8-phase fused GEMM ----------------
// LDS per operand: [buf 2][kk 2][row 256][32 bf16] planes; a K-half-tile
// (256x32 = 16KB) is one stage unit = 2 global_load_lds_dwordx4 per thread.
// Phases per K-tile: (kk0,MG0)(kk0,MG1)(kk1,MG0)(kk1,MG1); B-frags read at
// MG0, held in regs through MG1. Counted vmcnt(8) at phases 2,4 only.
__device__ __forceinline__ void stage_half(const unsigned short* src0,
                                           unsigned short* ldsbase, int tid) {
#pragma unroll
    for (int q = 0; q < 2; ++q)
        gload_lds16(src0 + (size_t)q * 128 * H, ldsbase + q * 4096 + tid * 8);
}

template<int BUF, int KK, int MG, int STG, int SBUF, int SKK, int WAITN>
__device__ __forceinline__ void phase4(unsigned short* As, unsigned short* Bs,
                                       const unsigned short* aSrc, const unsigned short* bSrc,
                                       int kt, int tid, int l15, int l4, int wm, int wn,
                                       bf16x8 (&bq)[4], f32x4 (&acc)[8][4]) {
    bf16x8 a[4];
#pragma unroll
    for (int mi = 0; mi < 4; ++mi) {
        int row = wm * 128 + (MG * 4 + mi) * 16 + l15;
        a[mi] = *(const bf16x8*)&As[BUF * 16384 + KK * 8192 + row * 32 + l4 * 8];
    }
    if (MG == 0) {
#pragma unroll
        for (int ni = 0; ni < 4; ++ni) {
            int row = wn * 64 + ni * 16 + l15;
            bq[ni] = *(const bf16x8*)&Bs[BUF * 16384 + KK * 8192 + row * 32 + l4 * 8];
        }
    }
    if (STG == 1) stage_half(aSrc + kt * 64 + SKK * 32, &As[SBUF * 16384 + SKK * 8192], tid);
    if (STG == 2) stage_half(bSrc + kt * 64 + SKK * 32, &Bs[SBUF * 16384 + SKK * 8192], tid);
    __builtin_amdgcn_s_barrier();
    __builtin_amdgcn_s_setprio(1);
#pragma unroll
    for (int mi = 0; mi < 4; ++mi)
#pragma unroll
        for (int ni = 0; ni < 4; ++ni)
            acc[MG * 4 + mi][ni] = __builtin_amdgcn_mfma_f32_16x16x32_bf16(
                a[mi], bq[ni], acc[MG * 4 + mi][ni], 0, 0, 0);
    __builtin_amdgcn_s_setprio(0);
    if constexpr (WAITN >= 0)
        asm volatile("s_waitcnt vmcnt(%0)" :: "n"(WAITN) : "memory");
    __builtin_amdgcn_s_barrier();
}

__global__ __launch_bounds__(512, 2) void gemm_logits4(const unsigned short* __restrict__ encBF,
                                                       const unsigned short* __restrict__ WeT,
                                                       const float* __restrict__ dvec,
                                                       const float* __restrict__ v,
                                                       float* __restrict__ part) {
    __shared__ unsigned short As[32768];   // 64 KB
    __shared__ unsigned short Bs[32768];   // 64 KB
    int tid = threadIdx.x, bid = blockIdx.x;
    int swz = (bid & 7) * 128 + (bid >> 3);   // XCD-chunked, bijective (1024 % 8 == 0)
    int bm = swz >> 2, bn = swz & 3;
    int lane = tid & 63, wid = tid >> 6;
    int wm = wid >> 2, wn = wid & 3;
    int l15 = lane & 15, l4 = lane >> 4;

    f32x4 acc[8][4] = {};
    bf16x8 bq[4];

    const unsigned short* aSrc = encBF + (size_t)(bm * 256 + (tid >> 2)) * H + (tid & 3) * 8;
    const unsigned short* bSrc = WeT + (size_t)(bn * 256 + (tid >> 2)) * H + (tid & 3) * 8;

    // prologue: kh0(0), kh1(0) -> buf0; kh0(1) -> buf1  (12 loads in flight)
    stage_half(aSrc + 0,  &As[0], tid);
    stage_half(bSrc + 0,  &Bs[0], tid);
    stage_half(aSrc + 32, &As[8192], tid);
    stage_half(bSrc + 32, &Bs[8192], tid);
    stage_half(aSrc + 64, &As[16384], tid);
    stage_half(bSrc + 64, &Bs[16384], tid);
    asm volatile("s_waitcnt vmcnt(8)" ::: "memory");   // kh0(0) landed
    __builtin_amdgcn_s_barrier();

    for (int it = 0; it < 7; ++it) {
        int t0 = 2 * it;
        // tile t0 (buf0): stage kh1(t0+1)->buf1 @ph1-2, kh0(t0+2)->buf0 @ph3-4
        phase4<0,0,0, 1,1,1, -1>(As, Bs, aSrc, bSrc, t0+1, tid, l15, l4, wm, wn, bq, acc);
        phase4<0,0,1, 2,1,1,  8>(As, Bs, aSrc, bSrc, t0+1, tid, l15, l4, wm, wn, bq, acc);
        phase4<0,1,0, 1,0,0, -1>(As, Bs, aSrc, bSrc, t0+2, tid, l15, l4, wm, wn, bq, acc);
        phase4<0,1,1, 2,0,0,  8>(As, Bs, aSrc, bSrc, t0+2, tid, l15, l4, wm, wn, bq, acc);
        // tile t0+1 (buf1): stage kh1(t0+2)->buf0, kh0(t0+3)->buf1
        phase4<1,0,0, 1,0,1, -1>(As, Bs, aSrc, bSrc, t0+2, tid, l15, l4, wm, wn, bq, acc);
        phase4<1,0,1, 2,0,1,  8>(As, Bs, aSrc, bSrc, t0+2, tid, l15, l4, wm, wn, bq, acc);
        phase4<1,1,0, 1,1,0, -1>(As, Bs, aSrc, bSrc, t0+3, tid, l15, l4, wm, wn, bq, acc);
        phase4<1,1,1, 2,1,0,  8>(As, Bs, aSrc, bSrc, t0+3, tid, l15, l4, wm, wn, bq, acc);
    }
    // tile 14 (buf0): stage kh1(15)->buf1 only; waits 8 then 4
    phase4<0,0,0, 1,1,1, -1>(As, Bs, aSrc, bSrc, 15, tid, l15, l4, wm, wn, bq, acc);
    phase4<0,0,1, 2,1,1,  8>(As, Bs, aSrc, bSrc, 15, tid, l15, l4, wm, wn, bq, acc);
    phase4<0,1,0, 0,0,0, -1>(As, Bs, aSrc, bSrc, 0,  tid, l15, l4, wm, wn, bq, acc);
    phase4<0,1,1, 0,0,0,  4>(As, Bs, aSrc, bSrc, 0,  tid, l15, l4, wm, wn, bq, acc);
    // tile 15 (buf1): no stages; drain kh1(15) at ph2
    phase4<1,0,0, 0,0,0, -1>(As, Bs, aSrc, bSrc, 0,  tid, l15, l4, wm, wn, bq, acc);
    phase4<1,0,1, 0,0,0,  0>(As, Bs, aSrc, bSrc, 0,  tid, l15, l4, wm, wn, bq, acc);
    phase4<1,1,0, 0,0,0, -1>(As, Bs, aSrc, bSrc, 0,  tid, l15, l4, wm, wn, bq, acc);
    phase4<1,1,1, 0,0,0, -1>(As, Bs, aSrc, bSrc, 0,  tid, l15, l4, wm, wn, bq, acc);

    // epilogue: partial logit over this wave's 64 j's
    float vj[4];
#pragma unroll
    for (int n = 0; n < 4; ++n) vj[n] = v[bn * 256 + wn * 64 + n * 16 + (lane & 15)];
#pragma unroll
    for (int m = 0; m < 8; ++m) {
#pragma unroll
        for (int i = 0; i < 4; ++i) {
            int rg = bm * 256 + wm * 128 + m * 16 + (lane >> 4) * 4 + i;
            int bb = rg & (B - 1);   // row = s*B + b
            float p = 0.f;
#pragma unroll
            for (int n = 0; n < 4; ++n) {
                int j = bn * 256 + wn * 64 + n * 16 + (lane & 15);
                p += vj[n] * tanhf(dvec[bb * H + j] + acc[m][n][i]);
            }
            p += __shfl_xor(p, 1);
            p += __shfl_xor(p, 2);
            p += __shfl_xor(p, 4);
            p += __shfl_xor(p, 8);
            if ((lane & 15) == 0) part[(size_t)rg * 16 + bn * 4 + wn] = p;
        }
    }
}

// ---------------- softmax over s per b ----------------
__global__ __launch_bounds__(256) void softmax_k(const float* __restrict__ part,
                                                 float* __restrict__ scores) {
    int b = blockIdx.x, tid = threadIdx.x;
    int lane = tid & 63, wid = tid >> 6;
    __shared__ float red[4];
    __shared__ float red2[4];
    float lg[8];
    float mx = -1e30f;
#pragma unroll
    for (int q = 0; q < 8; ++q) {
        int s = q * 256 + tid;
        const float4* pr = (const float4*)(part + ((size_t)(s * B + b)) * 16);
        float4 x = pr[0], y = pr[1], z = pr[2], w = pr[3];
        float L = (((x.x + x.y) + (x.z + x.w)) + ((y.x + y.y) + (y.z + y.w))) +
                  (((z.x + z.y) + (z.z + z.w)) + ((w.x + w.y) + (w.z + w.w)));
        lg[q] = L;
        mx = fmaxf(mx, L);
    }
#pragma unroll
    for (int off = 32; off; off >>= 1) mx = fmaxf(mx, __shfl_xor(mx, off));
    if (lane == 0) red[wid] = mx;
    __syncthreads();
    mx = fmaxf(fmaxf(red[0], red[1]), fmaxf(red[2], red[3]));
    float sum = 0.f;
#pragma unroll
    for (int q = 0; q < 8; ++q) {
        lg[q] = expf(lg[q] - mx);
        sum += lg[q];
    }
#pragma unroll
    for (int off = 32; off; off >>= 1) sum += __shfl_xor(sum, off);
    if (lane == 0) red2[wid] = sum;
    __syncthreads();
    sum = (red2[0] + red2[1]) + (red2[2] + red2[3]);
    float inv = 1.f / sum;
#pragma unroll
    for (int q = 0; q < 8; ++q) scores[b * S + q * 256 + tid] = lg[q] * inv;
}

// ---------------- attn_values partials: sum over an S-chunk ----------------
__global__ __launch_bounds__(256) void weighted_sum(const float* __restrict__ enc,
                                                    const float* __restrict__ scores,
                                                    float* __restrict__ part2) {
    __shared__ float sl[512];
    int t = threadIdx.x;
    int hx = blockIdx.x, b = blockIdx.y, sc = blockIdx.z;
    sl[t] = scores[b * S + sc * 512 + t];
    sl[t + 256] = scores[b * S + sc * 512 + t + 256];
    __syncthreads();
    int h = hx * 256 + t;
    const float* ep = enc + ((size_t)(sc * 512) * B) * H + (size_t)b * H + h;
    float acc = 0.f;
#pragma unroll 4
    for (int s = 0; s < 512; ++s) acc += ep[(size_t)s * B * H] * sl[s];
    part2[((size_t)sc * B + b) * H + h] = acc;
}

__global__ __launch_bounds__(256) void reduce_vals(const float* __restrict__ part2,
                                                   float* __restrict__ out) {
    int i = blockIdx.x * 256 + threadIdx.x;
    out[i] = (part2[i] + part2[B * H + i]) + (part2[2 * B * H + i] + part2[3 * B * H + i]);
}

extern "C" void kernel_launch(void* const* d_in, const int* in_sizes, int n_in,
                              void* d_out, int out_size, void* d_ws, size_t ws_size,
                              hipStream_t stream) {
    const float* dec = (const float*)d_in[0];   // [1,B,H]
    const float* enc = (const float*)d_in[1];   // [S,B,H]
    const float* Wd  = (const float*)d_in[2];   // [H,H]
    const float* We  = (const float*)d_in[3];   // [H,H]
    const float* v   = (const float*)d_in[4];   // [H]
    float* out = (float*)d_out;                 // [B*H] values, then [B*S] scores

    char* ws = (char*)d_ws;
    unsigned short* WeT = (unsigned short*)ws;                 // 2 MB
    float* dvec  = (float*)(ws + (2u << 20));                  // 128 KB
    float* part  = (float*)(ws + (3u << 20));                  // 4 MB
    float* part2 = (float*)(ws + (7u << 20));                  // 512 KB
    unsigned short* encBF = (unsigned short*)(ws + ((size_t)8 << 20));  // 128 MB

    transpose_we<<<dim3(16, 16), 256, 0, stream>>>(We, WeT);
    dec_proj<<<dim3(4, B), 256, 0, stream>>>(dec, Wd, dvec);
    convert_enc<<<2048, 256, 0, stream>>>(enc, encBF);
    gemm_logits4<<<1024, 512, 0, stream>>>(encBF, WeT, dvec, v, part);
    softmax_k<<<B, 256, 0, stream>>>(part, out + B * H);
    weighted_sum<<<dim3(4, B, 4), 256, 0, stream>>>(enc, out + B * H, part2);
    reduce_vals<<<128, 256, 0, stream>>>(part2, out);
}

// Round 6
// 473.529 us; speedup vs baseline: 1.0713x; 1.0006x over previous
//
#include <hip/hip_runtime.h>

#define H 1024
#define S 2048
#define B 32
#define M (S*B)

typedef short bf16x8 __attribute__((ext_vector_type(8)));
typedef float f32x4 __attribute__((ext_vector_type(4)));

__device__ __forceinline__ unsigned short f2bf(float f) {
    unsigned int u = __builtin_bit_cast(unsigned int, f);
    u += 0x7FFFu + ((u >> 16) & 1u);
    return (unsigned short)(u >> 16);
}

__device__ __forceinline__ void gload_lds16(const void* g, void* l) {
    __builtin_amdgcn_global_load_lds((const __attribute__((address_space(1))) void*)g,
                                     (__attribute__((address_space(3))) void*)l, 16, 0, 0);
}

// ---------------- enc f32 -> bf16 ----------------
__global__ __launch_bounds__(256) void convert_enc(const float* __restrict__ enc,
                                                   unsigned short* __restrict__ encBF) {
    const size_t total = (size_t)M * H / 8;
    for (size_t idx = (size_t)blockIdx.x * 256 + threadIdx.x; idx < total;
         idx += (size_t)gridDim.x * 256) {
        const float4* p = (const float4*)(enc + idx * 8);
        float4 x = p[0], y = p[1];
        bf16x8 c;
        c[0] = (short)f2bf(x.x); c[1] = (short)f2bf(x.y);
        c[2] = (short)f2bf(x.z); c[3] = (short)f2bf(x.w);
        c[4] = (short)f2bf(y.x); c[5] = (short)f2bf(y.y);
        c[6] = (short)f2bf(y.z); c[7] = (short)f2bf(y.w);
        *(bf16x8*)(encBF + idx * 8) = c;
    }
}

// ---------------- We -> We^T (bf16) ----------------
__global__ __launch_bounds__(256) void transpose_we(const float* __restrict__ We,
                                                    unsigned short* __restrict__ WeT) {
    __shared__ float t[64][65];
    int tx = threadIdx.x & 63, ty = threadIdx.x >> 6;
    int n0 = blockIdx.x * 64, k0 = blockIdx.y * 64;
#pragma unroll
    for (int q = 0; q < 16; ++q) {
        int kk = ty * 16 + q;
        t[kk][tx] = We[(size_t)(k0 + kk) * H + n0 + tx];
    }
    __syncthreads();
#pragma unroll
    for (int q = 0; q < 16; ++q) {
        int nn = ty * 16 + q;
        WeT[(size_t)(n0 + nn) * H + k0 + tx] = f2bf(t[tx][nn]);
    }
}

// ---------------- d[b][j] = dec[b] @ Wd ----------------
__global__ __launch_bounds__(256) void dec_proj(const float* __restrict__ dec,
                                                const float* __restrict__ Wd,
                                                float* __restrict__ dvec) {
    __shared__ float ds[H];
    int b = blockIdx.y, jc = blockIdx.x, t = threadIdx.x;
    for (int i = t; i < H; i += 256) ds[i] = dec[b * H + i];
    __syncthreads();
    int j = jc * 256 + t;
    float acc = 0.f;
#pragma unroll 8
    for (int h = 0; h < H; ++h) acc += ds[h] * Wd[(size_t)h * H + j];
    dvec[b * H + j] = acc;
}

// ---------------- 256x256 counted-vmcnt 8-phase fused GEMM ----------------
// LDS per operand: [buf 2][kk 2][row 256][slot 4 of 8 bf16]; physical slot =
// logical slot ^ (row&3). global_load_lds writes linearly (tid*16B), so the
// global SOURCE is pre-swizzled and the XOR is applied again on ds_read
// (rule 21: both sides or neither). Frag reads then hit 8 distinct bank
// quads per 16-lane group -> 2-way residual = free.
// Counted vmcnt(8) at phases 2,4 only; 8-12 loads always in flight.
__device__ __forceinline__ void stage_half(const unsigned short* src0,
                                           unsigned short* ldsbase, int tid) {
#pragma unroll
    for (int q = 0; q < 2; ++q)
        gload_lds16(src0 + (size_t)q * 128 * H, ldsbase + q * 4096 + tid * 8);
}

template<int BUF, int KK, int MG, int STG, int SBUF, int SKK, int WAITN>
__device__ __forceinline__ void phase4(unsigned short* As, unsigned short* Bs,
                                       const unsigned short* aSrc, const unsigned short* bSrc,
                                       int kt, int tid, int l15, int l4, int wm, int wn,
                                       bf16x8 (&bq)[4], f32x4 (&acc)[8][4]) {
    bf16x8 a[4];
#pragma unroll
    for (int mi = 0; mi < 4; ++mi) {
        int row = wm * 128 + (MG * 4 + mi) * 16 + l15;
        a[mi] = *(const bf16x8*)&As[BUF * 16384 + KK * 8192 + row * 32 + ((l4 ^ (row & 3)) * 8)];
    }
    if (MG == 0) {
#pragma unroll
        for (int ni = 0; ni < 4; ++ni) {
            int row = wn * 64 + ni * 16 + l15;
            bq[ni] = *(const bf16x8*)&Bs[BUF * 16384 + KK * 8192 + row * 32 + ((l4 ^ (row & 3)) * 8)];
        }
    }
    if (STG == 1) stage_half(aSrc + kt * 64 + SKK * 32, &As[SBUF * 16384 + SKK * 8192], tid);
    if (STG == 2) stage_half(bSrc + kt * 64 + SKK * 32, &Bs[SBUF * 16384 + SKK * 8192], tid);
    __builtin_amdgcn_s_barrier();
    __builtin_amdgcn_s_setprio(1);
#pragma unroll
    for (int mi = 0; mi < 4; ++mi)
#pragma unroll
        for (int ni = 0; ni < 4; ++ni)
            acc[MG * 4 + mi][ni] = __builtin_amdgcn_mfma_f32_16x16x32_bf16(
                a[mi], bq[ni], acc[MG * 4 + mi][ni], 0, 0, 0);
    __builtin_amdgcn_s_setprio(0);
    if constexpr (WAITN >= 0)
        asm volatile("s_waitcnt vmcnt(%0)" :: "n"(WAITN) : "memory");
    __builtin_amdgcn_s_barrier();
}

__global__ __launch_bounds__(512) void gemm_logits4(const unsigned short* __restrict__ encBF,
                                                    const unsigned short* __restrict__ WeT,
                                                    const float* __restrict__ dvec,
                                                    const float* __restrict__ v,
                                                    float* __restrict__ part) {
    __shared__ unsigned short As[32768];   // 64 KB
    __shared__ unsigned short Bs[32768];   // 64 KB
    int tid = threadIdx.x, bid = blockIdx.x;
    int swz = (bid & 7) * 128 + (bid >> 3);   // XCD-chunked, bijective (1024 % 8 == 0)
    int bm = swz >> 2, bn = swz & 3;
    int lane = tid & 63, wid = tid >> 6;
    int wm = wid >> 2, wn = wid & 3;
    int l15 = lane & 15, l4 = lane >> 4;

    f32x4 acc[8][4] = {};
    bf16x8 bq[4];

    // staging: thread tid -> LDS row tid>>2, physical slot tid&3; the global
    // source column is pre-swizzled so logical slot = (tid&3) ^ (row&3).
    int srow = tid >> 2;
    int sslot = (tid & 3) ^ (srow & 3);
    const unsigned short* aSrc = encBF + (size_t)(bm * 256 + srow) * H + sslot * 8;
    const unsigned short* bSrc = WeT + (size_t)(bn * 256 + srow) * H + sslot * 8;

    // prologue: kh0(0), kh1(0) -> buf0; kh0(1) -> buf1  (12 loads in flight)
    stage_half(aSrc + 0,  &As[0], tid);
    stage_half(bSrc + 0,  &Bs[0], tid);
    stage_half(aSrc + 32, &As[8192], tid);
    stage_half(bSrc + 32, &Bs[8192], tid);
    stage_half(aSrc + 64, &As[16384], tid);
    stage_half(bSrc + 64, &Bs[16384], tid);
    asm volatile("s_waitcnt vmcnt(8)" ::: "memory");   // kh0(0) landed
    __builtin_amdgcn_s_barrier();

    for (int it = 0; it < 7; ++it) {
        int t0 = 2 * it;
        // tile t0 (buf0): stage kh1(t0+1)->buf1 @ph1-2, kh0(t0+2)->buf0 @ph3-4
        phase4<0,0,0, 1,1,1, -1>(As, Bs, aSrc, bSrc, t0+1, tid, l15, l4, wm, wn, bq, acc);
        phase4<0,0,1, 2,1,1,  8>(As, Bs, aSrc, bSrc, t0+1, tid, l15, l4, wm, wn, bq, acc);
        phase4<0,1,0, 1,0,0, -1>(As, Bs, aSrc, bSrc, t0+2, tid, l15, l4, wm, wn, bq, acc);
        phase4<0,1,1, 2,0,0,  8>(As, Bs, aSrc, bSrc, t0+2, tid, l15, l4, wm, wn, bq, acc);
        // tile t0+1 (buf1): stage kh1(t0+2)->buf0, kh0(t0+3)->buf1
        phase4<1,0,0, 1,0,1, -1>(As, Bs, aSrc, bSrc, t0+2, tid, l15, l4, wm, wn, bq, acc);
        phase4<1,0,1, 2,0,1,  8>(As, Bs, aSrc, bSrc, t0+2, tid, l15, l4, wm, wn, bq, acc);
        phase4<1,1,0, 1,1,0, -1>(As, Bs, aSrc, bSrc, t0+3, tid, l15, l4, wm, wn, bq, acc);
        phase4<1,1,1, 2,1,0,  8>(As, Bs, aSrc, bSrc, t0+3, tid, l15, l4, wm, wn, bq, acc);
    }
    // tile 14 (buf0): stage kh1(15)->buf1 only; waits 8 then 4
    phase4<0,0,0, 1,1,1, -1>(As, Bs, aSrc, bSrc, 15, tid, l15, l4, wm, wn, bq, acc);
    phase4<0,0,1, 2,1,1,  8>(As, Bs, aSrc, bSrc, 15, tid, l15, l4, wm, wn, bq, acc);
    phase4<0,1,0, 0,0,0, -1>(As, Bs, aSrc, bSrc, 0,  tid, l15, l4, wm, wn, bq, acc);
    phase4<0,1,1, 0,0,0,  4>(As, Bs, aSrc, bSrc, 0,  tid, l15, l4, wm, wn, bq, acc);
    // tile 15 (buf1): no stages; drain kh1(15) at ph2
    phase4<1,0,0, 0,0,0, -1>(As, Bs, aSrc, bSrc, 0,  tid, l15, l4, wm, wn, bq, acc);
    phase4<1,0,1, 0,0,0,  0>(As, Bs, aSrc, bSrc, 0,  tid, l15, l4, wm, wn, bq, acc);
    phase4<1,1,0, 0,0,0, -1>(As, Bs, aSrc, bSrc, 0,  tid, l15, l4, wm, wn, bq, acc);
    phase4<1,1,1, 0,0,0, -1>(As, Bs, aSrc, bSrc, 0,  tid, l15, l4, wm, wn, bq, acc);

    // epilogue: partial logit over this wave's 64 j's
    float vj[4];
#pragma unroll
    for (int n = 0; n < 4; ++n) vj[n] = v[bn * 256 + wn * 64 + n * 16 + (lane & 15)];
#pragma unroll
    for (int m = 0; m < 8; ++m) {
#pragma unroll
        for (int i = 0; i < 4; ++i) {
            int rg = bm * 256 + wm * 128 + m * 16 + (lane >> 4) * 4 + i;
            int bb = rg & (B - 1);   // row = s*B + b
            float p = 0.f;
#pragma unroll
            for (int n = 0; n < 4; ++n) {
                int j = bn * 256 + wn * 64 + n * 16 + (lane & 15);
                p += vj[n] * tanhf(dvec[bb * H + j] + acc[m][n][i]);
            }
            p += __shfl_xor(p, 1);
            p += __shfl_xor(p, 2);
            p += __shfl_xor(p, 4);
            p += __shfl_xor(p, 8);
            if ((lane & 15) == 0) part[(size_t)rg * 16 + bn * 4 + wn] = p;
        }
    }
}

// ---------------- softmax over s per b ----------------
__global__ __launch_bounds__(256) void softmax_k(const float* __restrict__ part,
                                                 float* __restrict__ scores) {
    int b = blockIdx.x, tid = threadIdx.x;
    int lane = tid & 63, wid = tid >> 6;
    __shared__ float red[4];
    __shared__ float red2[4];
    float lg[8];
    float mx = -1e30f;
#pragma unroll
    for (int q = 0; q < 8; ++q) {
        int s = q * 256 + tid;
        const float4* pr = (const float4*)(part + ((size_t)(s * B + b)) * 16);
        float4 x = pr[0], y = pr[1], z = pr[2], w = pr[3];
        float L = (((x.x + x.y) + (x.z + x.w)) + ((y.x + y.y) + (y.z + y.w))) +
                  (((z.x + z.y) + (z.z + z.w)) + ((w.x + w.y) + (w.z + w.w)));
        lg[q] = L;
        mx = fmaxf(mx, L);
    }
#pragma unroll
    for (int off = 32; off; off >>= 1) mx = fmaxf(mx, __shfl_xor(mx, off));
    if (lane == 0) red[wid] = mx;
    __syncthreads();
    mx = fmaxf(fmaxf(red[0], red[1]), fmaxf(red[2], red[3]));
    float sum = 0.f;
#pragma unroll
    for (int q = 0; q < 8; ++q) {
        lg[q] = expf(lg[q] - mx);
        sum += lg[q];
    }
#pragma unroll
    for (int off = 32; off; off >>= 1) sum += __shfl_xor(sum, off);
    if (lane == 0) red2[wid] = sum;
    __syncthreads();
    sum = (red2[0] + red2[1]) + (red2[2] + red2[3]);
    float inv = 1.f / sum;
#pragma unroll
    for (int q = 0; q < 8; ++q) scores[b * S + q * 256 + tid] = lg[q] * inv;
}

// ---------------- attn_values partials: sum over an S-chunk ----------------
__global__ __launch_bounds__(256) void weighted_sum(const float* __restrict__ enc,
                                                    const float* __restrict__ scores,
                                                    float* __restrict__ part2) {
    __shared__ float sl[512];
    int t = threadIdx.x;
    int hx = blockIdx.x, b = blockIdx.y, sc = blockIdx.z;
    sl[t] = scores[b * S + sc * 512 + t];
    sl[t + 256] = scores[b * S + sc * 512 + t + 256];
    __syncthreads();
    int h = hx * 256 + t;
    const float* ep = enc + ((size_t)(sc * 512) * B) * H + (size_t)b * H + h;
    float acc = 0.f;
#pragma unroll 4
    for (int s = 0; s < 512; ++s) acc += ep[(size_t)s * B * H] * sl[s];
    part2[((size_t)sc * B + b) * H + h] = acc;
}

__global__ __launch_bounds__(256) void reduce_vals(const float* __restrict__ part2,
                                                   float* __restrict__ out) {
    int i = blockIdx.x * 256 + threadIdx.x;
    out[i] = (part2[i] + part2[B * H + i]) + (part2[2 * B * H + i] + part2[3 * B * H + i]);
}

extern "C" void kernel_launch(void* const* d_in, const int* in_sizes, int n_in,
                              void* d_out, int out_size, void* d_ws, size_t ws_size,
                              hipStream_t stream) {
    const float* dec = (const float*)d_in[0];   // [1,B,H]
    const float* enc = (const float*)d_in[1];   // [S,B,H]
    const float* Wd  = (const float*)d_in[2];   // [H,H]
    const float* We  = (const float*)d_in[3];   // [H,H]
    const float* v   = (const float*)d_in[4];   // [H]
    float* out = (float*)d_out;                 // [B*H] values, then [B*S] scores

    char* ws = (char*)d_ws;
    unsigned short* WeT = (unsigned short*)ws;                 // 2 MB
    float* dvec  = (float*)(ws + (2u << 20));                  // 128 KB
    float* part  = (float*)(ws + (3u << 20));                  // 4 MB
    float* part2 = (float*)(ws + (7u << 20));                  // 512 KB
    unsigned short* encBF = (unsigned short*)(ws + ((size_t)8 << 20));  // 128 MB

    transpose_we<<<dim3(16, 16), 256, 0, stream>>>(We, WeT);
    dec_proj<<<dim3(4, B), 256, 0, stream>>>(dec, Wd, dvec);
    convert_enc<<<2048, 256, 0, stream>>>(enc, encBF);
    gemm_logits4<<<1024, 512, 0, stream>>>(encBF, WeT, dvec, v, part);
    softmax_k<<<B, 256, 0, stream>>>(part, out + B * H);
    weighted_sum<<<dim3(4, B, 4), 256, 0, stream>>>(enc, out + B * H, part2);
    reduce_vals<<<128, 256, 0, stream>>>(part2, out);
}